// Round 12
// baseline (1751.117 us; speedup 1.0000x reference)
//
#include <hip/hip_runtime.h>
#include <hip/hip_bf16.h>
#include <stdint.h>

// DeepFakeDetectionModel: stem LN(26)->Linear(26->1024)->ReLU, 8x [LN->Linear(1024->1024)->ReLU],
// head LN->Linear(1024->1)->sigmoid.  B=65536.
//
// LN folded into weights; GEMMs on RAW fp16 activations; LN affine in epilogue via per-row stats.
// R2-R10: every LDS/barrier-schedule/occupancy variant plateaus at ~750 TF (MfmaUtil ~31%
//   invariant). Common element: LDS staging + per-tile block barriers lockstep the waves.
// R11: BARRIER-FREE, LDS-FREE main loop. Activations stored in A-FRAGMENT-MAJOR packed layout
//   hP[rb][kc][lane][8] (lane l of frag (rb,kc) = h[row=rb*32+(l&31)][k=kc*16+(l>>5)*8+j]) --
//   written by the producer's epilogue. W pre-packed B-fragment-major (R9). Both operands are
//   single coalesced 16B/lane loads (1KB/wave contiguous) from L2. 32x32x16 MFMA (+20% FLOP/cyc,
//   half the instructions; C/D: col=lane&31, row=(reg&3)+8*(reg>>2)+4*(lane>>5)). Per-wave
//   even/odd reg double-buffer + counted vmcnt(8); waves fully independent.

typedef __attribute__((ext_vector_type(8))) _Float16 f16x8;
typedef __attribute__((ext_vector_type(4))) float f32x4;
typedef __attribute__((ext_vector_type(16))) float f32x16;

#define EPSLN 1e-5f
#define HDIM 1024

__device__ __forceinline__ void gload16(const void* g, void* l) {
  __builtin_amdgcn_global_load_lds(
      (const __attribute__((address_space(1))) unsigned int*)g,
      (__attribute__((address_space(3))) unsigned int*)l, 16, 0, 0);
}

// ---------------- zero stats ----------------
__global__ __launch_bounds__(256) void zero_f32(float* __restrict__ p, int n) {
  int i = blockIdx.x * 256 + threadIdx.x;
  if (i < n) p[i] = 0.f;
}

// ---------------- fold block scalars: S'=sum(fp16(gamma*W)), b'=b+beta@W ----------------
__global__ __launch_bounds__(256) void fold_blk(
    const float* __restrict__ bg, const float* __restrict__ bb,
    const float* __restrict__ bw, const float* __restrict__ bbias,
    float* __restrict__ bfold, float* __restrict__ Sfold) {
  int lo = blockIdx.x;            // layer*1024 + o
  int layer = lo >> 10;
  const float* wrow = bw + (size_t)lo * HDIM;
  const float* g = bg + (size_t)layer * HDIM;
  const float* be = bb + (size_t)layer * HDIM;
  int t = threadIdx.x;
  float s = 0.f, acb = 0.f;
  for (int i = t; i < HDIM; i += 256) {
    float wv = wrow[i];
    _Float16 wp = (_Float16)(wv * g[i]);   // same rounding as fold_pack32 -> S' consistent
    s += (float)wp;
    acb += be[i] * wv;
  }
#pragma unroll
  for (int off = 1; off < 64; off <<= 1) { s += __shfl_xor(s, off); acb += __shfl_xor(acb, off); }
  __shared__ float rs[4], rb[4];
  int l = t & 63, w = t >> 6;
  if (l == 0) { rs[w] = s; rb[w] = acb; }
  __syncthreads();
  if (t == 0) {
    Sfold[lo] = rs[0] + rs[1] + rs[2] + rs[3];
    bfold[lo] = bbias[lo] + rb[0] + rb[1] + rb[2] + rb[3];
  }
}

// ---------------- pack W' B-fragment-major for 32x32x16: Wf32[lay][n32][kc][lane][8] ----------------
// lane l of frag (n32,kc) holds W'[col = n32*32 + (l&31)][k = kc*16 + (l>>5)*8 + j].
__global__ __launch_bounds__(256) void fold_pack32(
    const float* __restrict__ bg, const float* __restrict__ bw,
    _Float16* __restrict__ Wf) {
  size_t tid = (size_t)blockIdx.x * 256 + threadIdx.x;  // L*131072 octets
  int lay = (int)(tid >> 17);
  int oct = (int)(tid & 131071);
  int frag = oct >> 6, lane = oct & 63;   // frag = n32*64 + kc
  int n32 = frag >> 6, kc = frag & 63;
  int col = n32 * 32 + (lane & 31);
  int kbase = kc * 16 + ((lane >> 5) << 3);
  const float* wrow = bw + ((size_t)lay << 20) + (size_t)col * HDIM + kbase;
  const float* g = bg + (size_t)lay * HDIM + kbase;
  f16x8 v;
#pragma unroll
  for (int j = 0; j < 8; ++j) v[j] = (_Float16)(wrow[j] * g[j]);
  *(f16x8*)(Wf + tid * 8) = v;
}

// ---------------- fold head ----------------
__global__ __launch_bounds__(256) void fold_head(
    const float* __restrict__ lg, const float* __restrict__ lb,
    const float* __restrict__ lw, const float* __restrict__ lbias,
    float* __restrict__ headW, float* __restrict__ headAux) {
  int t = threadIdx.x;
  float s = 0.f, acb = 0.f;
  for (int i = t; i < HDIM; i += 256) {
    float wp = lw[i] * lg[i];
    headW[i] = wp;
    s += wp;
    acb += lb[i] * lw[i];
  }
#pragma unroll
  for (int off = 1; off < 64; off <<= 1) { s += __shfl_xor(s, off); acb += __shfl_xor(acb, off); }
  __shared__ float rs[4], rb[4];
  int l = t & 63, w = t >> 6;
  if (l == 0) { rs[w] = s; rb[w] = acb; }
  __syncthreads();
  if (t == 0) {
    headAux[0] = rs[0] + rs[1] + rs[2] + rs[3];
    headAux[1] = lbias[0] + rb[0] + rb[1] + rb[2] + rb[3];
  }
}

// ---------------- stem weight pad+cast, PRE-SWIZZLED storage (for stem's LDS path) ----------------
__global__ __launch_bounds__(256) void fold_stem(const float* __restrict__ stw,
                                                 _Float16* __restrict__ Wst) {
  int idx = blockIdx.x * 256 + threadIdx.x;   // 1024*64
  int o = idx >> 6, j = idx & 63;
  int i = (((j >> 3) ^ (o & 7)) << 3) + (j & 7);
  Wst[idx] = (i < 26) ? (_Float16)stw[o * 26 + i] : (_Float16)0.f;
}

// ---------------- fused stem: LN(26) + GEMM K=64 (16x16 MFMA) + bias/relu + PACKED store + stats ----------------
__global__ __launch_bounds__(256) void stem_gemm(
    const float* __restrict__ x, const float* __restrict__ stg, const float* __restrict__ stb,
    const _Float16* __restrict__ Wst, const float* __restrict__ stbias,
    _Float16* __restrict__ hP, float* __restrict__ stats_out, int rowBase) {
  __shared__ float xin[128 * 26];
  __shared__ _Float16 As[128 * 64];
  __shared__ _Float16 Bs[128 * 64];
  const int t = threadIdx.x;
  const int l = t & 63;
  const int w = t >> 6;
  const int wm = w >> 1, wn = w & 1;
  const int brow = blockIdx.x * 128;
  const int bcol = blockIdx.y * 128;

  const _Float16* gb = Wst + (size_t)(bcol + (t >> 3)) * 64 + (t & 7) * 8;
  char* lB = (char*)Bs + (size_t)w * 1024;
#pragma unroll
  for (int q = 0; q < 4; ++q) gload16(gb + (size_t)q * 32 * 64, lB + q * 4096);

  const float* src = x + ((size_t)rowBase + brow) * 26;
  for (int i = t; i < 128 * 26; i += 256) xin[i] = src[i];
  __syncthreads();

  if (t < 128) {
    float m = 0.f;
#pragma unroll
    for (int i = 0; i < 26; ++i) m += xin[t * 26 + i];
    m *= (1.f / 26.f);
    float v = 0.f;
#pragma unroll
    for (int i = 0; i < 26; ++i) { float d = xin[t * 26 + i] - m; v += d * d; }
    float rstd = rsqrtf(v * (1.f / 26.f) + EPSLN);
    _Float16 tmp[32];
#pragma unroll
    for (int i = 0; i < 26; ++i)
      tmp[i] = (_Float16)((xin[t * 26 + i] - m) * rstd * stg[i] + stb[i]);
#pragma unroll
    for (int i = 26; i < 32; ++i) tmp[i] = (_Float16)0.f;
    char* arow = (char*)As + t * 128;
#pragma unroll
    for (int c = 0; c < 4; ++c) {
      f16x8 vv;
#pragma unroll
      for (int j = 0; j < 8; ++j) vv[j] = tmp[c * 8 + j];
      *(f16x8*)(arow + ((c ^ (t & 7)) << 4)) = vv;
    }
    f16x8 vz = (f16x8)(_Float16)0.f;
#pragma unroll
    for (int c = 4; c < 8; ++c) *(f16x8*)(arow + ((c ^ (t & 7)) << 4)) = vz;
  }
  __syncthreads();

  f32x4 acc[4][4];
#pragma unroll
  for (int i = 0; i < 4; ++i)
#pragma unroll
    for (int j = 0; j < 4; ++j) acc[i][j] = (f32x4){0.f, 0.f, 0.f, 0.f};

#pragma unroll
  for (int ks = 0; ks < 2; ++ks) {
    const int cx = ((ks * 4 + (l >> 4)) ^ (l & 7)) << 4;
    f16x8 af[4], bfr[4];
#pragma unroll
    for (int m = 0; m < 4; ++m)
      af[m] = *(const f16x8*)((const char*)As + (wm * 64 + m * 16 + (l & 15)) * 128 + cx);
#pragma unroll
    for (int n = 0; n < 4; ++n)
      bfr[n] = *(const f16x8*)((const char*)Bs + (wn * 64 + n * 16 + (l & 15)) * 128 + cx);
#pragma unroll
    for (int m = 0; m < 4; ++m)
#pragma unroll
      for (int n = 0; n < 4; ++n)
        acc[m][n] = __builtin_amdgcn_mfma_f32_16x16x32_f16(af[m], bfr[n], acc[m][n], 0, 0, 0);
  }

  __syncthreads();
  float* sred = (float*)xin;     // 128 rows x {sum,sumsq}
  if (t < 256) sred[t] = 0.f;
  __syncthreads();

  float Bf[4];
#pragma unroll
  for (int n = 0; n < 4; ++n) Bf[n] = stbias[bcol + wn * 64 + n * 16 + (l & 15)];
#pragma unroll
  for (int m = 0; m < 4; ++m) {
#pragma unroll
    for (int rg = 0; rg < 4; ++rg) {
      int rloc = wm * 64 + m * 16 + (l >> 4) * 4 + rg;
      int rbW = (brow >> 5) + (rloc >> 5);
      float ps = 0.f, psq = 0.f;
#pragma unroll
      for (int n = 0; n < 4; ++n) {
        int col = bcol + wn * 64 + n * 16 + (l & 15);
        float vv = fmaxf(acc[m][n][rg] + Bf[n], 0.f);
        // packed A-frag-major store: hP[rb][kc][(r&31)+32*hw][j]
        size_t flat = (((size_t)rbW * 64 + (col >> 4)) * 64 +
                       ((rloc & 31) + 32 * ((l >> 3) & 1))) * 8 + (l & 7);
        hP[flat] = (_Float16)vv;
        ps += vv; psq += vv * vv;
      }
#pragma unroll
      for (int off = 1; off < 16; off <<= 1) {
        ps += __shfl_xor(ps, off);
        psq += __shfl_xor(psq, off);
      }
      if ((l & 15) == 0) {
        atomicAdd(&sred[rloc * 2 + 0], ps);
        atomicAdd(&sred[rloc * 2 + 1], psq);
      }
    }
  }
  __syncthreads();
  if (t < 256) atomicAdd(&stats_out[(size_t)(brow + (t >> 1)) * 2 + (t & 1)], sred[t]);
}

// ---------------- per-layer GEMM: barrier-free, LDS-free, 32x32x16 MFMA ----------------
// 256 thr = 4 waves (2M x 2N); per-wave 64x64 = acc 2x2 x f32x16. Per BK=32 tile per wave:
// 4 A-frag + 4 B-frag coalesced 16B/lane loads (1KB/wave each, from L2) + 8 MFMA. Even/odd
// reg double-buffer, s_waitcnt vmcnt(8) (+sched_barrier, rule #18). NO s_barrier in main loop.
__global__ __launch_bounds__(256) void layer32(
    const _Float16* __restrict__ hPin, const float* __restrict__ stats_in,
    const _Float16* __restrict__ Wf, const float* __restrict__ bfold,
    const float* __restrict__ Sfold, _Float16* __restrict__ hPout,
    float* __restrict__ stats_out) {
  __shared__ float mrstd[256];
  __shared__ float sred[256];
  const int t = threadIdx.x;
  const int l = t & 63;
  const int w = t >> 6;
  const int wm = w >> 1, wn = w & 1;
  int bid = blockIdx.x;
  {  // XCD chunk swizzle (A-panel groups share one L2)
    int nb = gridDim.x;
    if ((nb & 7) == 0) { int cpx = nb >> 3; bid = (bid & 7) * cpx + (bid >> 3); }
  }
  const int brow = (bid >> 3) * 128;   // 8 consecutive bids share the A-panel
  const int bcol = (bid & 7) * 128;

  // per-row LN constants for the block's 128 rows
  if (t < 128) {
    float sum = stats_in[(size_t)(brow + t) * 2 + 0];
    float sumsq = stats_in[(size_t)(brow + t) * 2 + 1];
    float mean = sum * (1.f / 1024.f);
    mrstd[t * 2 + 0] = mean;
    mrstd[t * 2 + 1] = rsqrtf(sumsq * (1.f / 1024.f) - mean * mean + EPSLN);
  }
  sred[t] = 0.f;
  __syncthreads();

  f32x16 acc[2][2];
#pragma unroll
  for (int i = 0; i < 2; ++i)
#pragma unroll
    for (int j = 0; j < 2; ++j)
#pragma unroll
      for (int e = 0; e < 16; ++e) acc[i][j][e] = 0.f;

  const int rb0 = (brow >> 5) + wm * 2;
  const int n0 = (bcol >> 5) + wn * 2;
  const _Float16* Abase = hPin + ((size_t)rb0 * 4096 + l) * 8;  // frag(pm,kc2): +pm*32768+kc2*512
  const _Float16* Bbase = Wf + ((size_t)n0 * 4096 + l) * 8;

  f16x8 A0[2][2], B0[2][2], A1[2][2], B1[2][2];

#define LOADT(A_, B_, kt)                                                        \
  do {                                                                           \
    const int kc2 = (kt) * 2;                                                    \
    _Pragma("unroll") for (int pm = 0; pm < 2; ++pm)                             \
        _Pragma("unroll") for (int h = 0; h < 2; ++h)                            \
            A_[pm][h] = *(const f16x8*)(Abase + pm * 32768 + (kc2 + h) * 512);   \
    _Pragma("unroll") for (int pn = 0; pn < 2; ++pn)                             \
        _Pragma("unroll") for (int h = 0; h < 2; ++h)                            \
            B_[pn][h] = *(const f16x8*)(Bbase + pn * 32768 + (kc2 + h) * 512);   \
  } while (0)
#define COMPUTE(A_, B_)                                                          \
  do {                                                                           \
    __builtin_amdgcn_s_setprio(1);                                               \
    _Pragma("unroll") for (int pm = 0; pm < 2; ++pm)                             \
        _Pragma("unroll") for (int pn = 0; pn < 2; ++pn) {                       \
      acc[pm][pn] = __builtin_amdgcn_mfma_f32_32x32x16_f16(A_[pm][0], B_[pn][0], \
                                                           acc[pm][pn], 0, 0, 0);\
      acc[pm][pn] = __builtin_amdgcn_mfma_f32_32x32x16_f16(A_[pm][1], B_[pn][1], \
                                                           acc[pm][pn], 0, 0, 0);\
    }                                                                            \
    __builtin_amdgcn_s_setprio(0);                                               \
  } while (0)
#define WAITN(N)                                                \
  do {                                                          \
    asm volatile("s_waitcnt vmcnt(" #N ")" ::: "memory");       \
    __builtin_amdgcn_sched_barrier(0);                          \
  } while (0)

  LOADT(A0, B0, 0);
#pragma unroll 1
  for (int kt2 = 0; kt2 < 15; ++kt2) {
    LOADT(A1, B1, 2 * kt2 + 1);
    WAITN(8);
    COMPUTE(A0, B0);
    LOADT(A0, B0, 2 * kt2 + 2);
    WAITN(8);
    COMPUTE(A1, B1);
  }
  LOADT(A1, B1, 31);
  WAITN(8);
  COMPUTE(A0, B0);   // tile 30
  WAITN(0);
  COMPUTE(A1, B1);   // tile 31

#undef LOADT
#undef COMPUTE
#undef WAITN

  // ---- epilogue: LN-affine + relu + PACKED fp16 store + stats (LDS combine) ----
  float Sc[2], Bc[2];
#pragma unroll
  for (int pn = 0; pn < 2; ++pn) {
    int col = bcol + wn * 64 + pn * 32 + (l & 31);
    Sc[pn] = Sfold[col];
    Bc[pn] = bfold[col];
  }
  const int hw = (l >> 3) & 1, jj = l & 7;
#pragma unroll
  for (int pm = 0; pm < 2; ++pm) {
    const int rbW = (brow >> 5) + wm * 2 + pm;
#pragma unroll
    for (int reg = 0; reg < 16; ++reg) {
      int rr = (reg & 3) + 8 * (reg >> 2) + 4 * (l >> 5);  // 0..31 (C/D row, m74/m101)
      int rloc = wm * 64 + pm * 32 + rr;
      float mean = mrstd[rloc * 2 + 0];
      float rstd = mrstd[rloc * 2 + 1];
      float s = 0.f, sq = 0.f;
#pragma unroll
      for (int pn = 0; pn < 2; ++pn) {
        float vv = rstd * (acc[pm][pn][reg] - mean * Sc[pn]) + Bc[pn];
        vv = fmaxf(vv, 0.f);
        int kc = (bcol >> 4) + wn * 4 + pn * 2 + ((l >> 4) & 1);
        size_t flat = (((size_t)rbW * 64 + kc) * 64 + (rr + 32 * hw)) * 8 + jj;
        hPout[flat] = (_Float16)vv;
        s += vv; sq += vv * vv;
      }
#pragma unroll
      for (int off = 1; off < 32; off <<= 1) {   // reduce over l&31 (cols)
        s += __shfl_xor(s, off);
        sq += __shfl_xor(sq, off);
      }
      if ((l & 31) == 0) {
        atomicAdd(&sred[rloc * 2 + 0], s);
        atomicAdd(&sred[rloc * 2 + 1], sq);
      }
    }
  }
  __syncthreads();
  atomicAdd(&stats_out[(size_t)(brow + (t >> 1)) * 2 + (t & 1)], sred[t]);
}

// ---------------- head: packed h8 read; out = sigmoid(rstd*(h8@W'' - mean*S'') + b'') ----------------
__global__ __launch_bounds__(512) void head_kernel(
    const _Float16* __restrict__ h8P, const float* __restrict__ stats8,
    const float* __restrict__ headW, const float* __restrict__ headAux,
    float* __restrict__ out, int rowBase) {
  int t = threadIdx.x, l = t & 63, w = t >> 6;
  int lrow = blockIdx.x * 8 + w;
  const _Float16* hp = h8P + (((size_t)(lrow >> 5) * 64 + l) * 64 + (lrow & 31)) * 8;
  f16x8 v0 = *(const f16x8*)hp;            // k = l*16 + 0..7
  f16x8 v1 = *(const f16x8*)(hp + 256);    // k = l*16 + 8..15  (lane-slot +32 -> +32*8 elems)
  float acc = 0.f;
#pragma unroll
  for (int j = 0; j < 8; ++j) acc += (float)v0[j] * headW[l * 16 + j];
#pragma unroll
  for (int j = 0; j < 8; ++j) acc += (float)v1[j] * headW[l * 16 + 8 + j];
#pragma unroll
  for (int off = 1; off < 64; off <<= 1) acc += __shfl_xor(acc, off);
  if (l == 0) {
    float sum = stats8[lrow * 2 + 0], sumsq = stats8[lrow * 2 + 1];
    float mean = sum * (1.f / 1024.f);
    float rstd = rsqrtf(sumsq * (1.f / 1024.f) - mean * mean + EPSLN);
    float z = rstd * (acc - mean * headAux[0]) + headAux[1];
    out[rowBase + lrow] = 1.f / (1.f + expf(-z));
  }
}

extern "C" void kernel_launch(void* const* d_in, const int* in_sizes, int n_in,
                              void* d_out, int out_size, void* d_ws, size_t ws_size,
                              hipStream_t stream) {
  const float* x      = (const float*)d_in[0];
  const float* stg    = (const float*)d_in[1];
  const float* stb    = (const float*)d_in[2];
  const float* stw    = (const float*)d_in[3];
  const float* stbias = (const float*)d_in[4];
  const float* bg     = (const float*)d_in[5];
  const float* bb     = (const float*)d_in[6];
  const float* bw     = (const float*)d_in[7];
  const float* bbias  = (const float*)d_in[8];
  const float* lg     = (const float*)d_in[9];
  const float* lb     = (const float*)d_in[10];
  const float* lw     = (const float*)d_in[11];
  const float* lbias  = (const float*)d_in[12];
  float* out = (float*)d_out;
  const int B = 65536;
  const int L = 8;

  char* ws = (char*)d_ws;
  size_t off = 0;
  auto carve = [&](size_t bytes) -> char* {
    char* p = ws + off;
    off = (off + bytes + 255) & ~(size_t)255;
    return p;
  };
  _Float16* Wf32  = (_Float16*)carve((size_t)L * HDIM * HDIM * 2);
  float* bfold   = (float*)carve((size_t)L * HDIM * 4);
  float* Sfold   = (float*)carve((size_t)L * HDIM * 4);
  float* headW   = (float*)carve((size_t)HDIM * 4);
  float* headAux = (float*)carve(256);
  _Float16* Wst  = (_Float16*)carve((size_t)HDIM * 64 * 2);
  size_t fixed = off;

  // pick largest batch chunk R (power of 2, >=256) whose buffers fit in ws
  int R = B;
  while (R > 256) {
    size_t need = fixed + 2 * ((size_t)R * HDIM * 2 + 256) + ((size_t)9 * R * 2 * 4 + 256);
    if (need <= ws_size) break;
    R >>= 1;
  }
  _Float16* hA = (_Float16*)carve((size_t)R * HDIM * 2);
  _Float16* hB = (_Float16*)carve((size_t)R * HDIM * 2);
  float* stats = (float*)carve((size_t)9 * R * 2 * 4);  // 9 slots: h0..h8 (sum,sumsq)

  fold_blk<<<L * HDIM, 256, 0, stream>>>(bg, bb, bw, bbias, bfold, Sfold);
  fold_pack32<<<(L * 131072) / 256, 256, 0, stream>>>(bg, bw, Wf32);
  fold_head<<<1, 256, 0, stream>>>(lg, lb, lw, lbias, headW, headAux);
  fold_stem<<<HDIM * 64 / 256, 256, 0, stream>>>(stw, Wst);

  const int nstats = 9 * R * 2;
  for (int c = 0; c < B / R; ++c) {
    int rowBase = c * R;
    zero_f32<<<(nstats + 255) / 256, 256, 0, stream>>>(stats, nstats);
    {
      dim3 grid(R / 128, 8);
      stem_gemm<<<grid, 256, 0, stream>>>(x, stg, stb, Wst, stbias, hA, stats, rowBase);
    }
    _Float16* cur = hA;
    _Float16* nxt = hB;
    for (int lyr = 0; lyr < L; ++lyr) {
      int nb = (R / 128) * 8;
      layer32<<<nb, 256, 0, stream>>>(
          cur, stats + (size_t)lyr * R * 2, Wf32 + (size_t)lyr * HDIM * HDIM,
          bfold + lyr * HDIM, Sfold + lyr * HDIM, nxt, stats + (size_t)(lyr + 1) * R * 2);
      _Float16* tmp = cur; cur = nxt; nxt = tmp;
    }
    head_kernel<<<R / 8, 512, 0, stream>>>(cur, stats + (size_t)8 * R * 2, headW, headAux, out, rowBase);
  }
}